// Round 9
// baseline (672.189 us; speedup 1.0000x reference)
//
#include <hip/hip_runtime.h>
#include <math.h>

typedef _Float16 f16;
typedef f16 f16x4 __attribute__((ext_vector_type(4)));
typedef f16 f16x8 __attribute__((ext_vector_type(8)));
typedef float f32x4 __attribute__((ext_vector_type(4)));

namespace {

constexpr int kB  = 32;
constexpr int kL  = 1024;
constexpr int kH  = 512;
constexpr int kP  = 336;
constexpr int kNL = 3;
constexpr int kNS = 32;
constexpr int kM  = 16;   // chunks per row (L/64)

// async global->LDS, 16B per lane. LDS dest is wave-uniform base + lane*16.
__device__ __forceinline__ void llds16(const void* g, void* s) {
  __builtin_amdgcn_global_load_lds((const __attribute__((address_space(1))) void*)g,
                                   (__attribute__((address_space(3))) void*)s, 16, 0, 0);
}

__device__ __forceinline__ float gelu_tanh(float y0) {
  float x3 = y0 * y0 * y0;
  float a = 0.7978845608028654f * fmaf(0.044715f, x3, y0);
  float aa = fminf(a, 15.f);
  float ex = __expf(2.f * aa);
  float th = 1.f - 2.f / (ex + 1.f);
  return 0.5f * y0 * (1.f + th);
}

// ---------------------------------------------------------------------------
// K_pre: per (layer,h) build chunked-scan operands (see R6 notes).
// ---------------------------------------------------------------------------
__global__ __launch_bounds__(64) void prep_kernel(
    const float* __restrict__ log_dt, const float* __restrict__ A_re,
    const float* __restrict__ A_im, const float* __restrict__ C_re,
    const float* __restrict__ C_im, const float* __restrict__ Dskip,
    f16* __restrict__ Afrag_c, f16* __restrict__ Afrag_a,
    float* __restrict__ rT) {
  int lh = blockIdx.x;   // layer*H + h
  int tid = threadIdx.x; // 0..63
  __shared__ float pr[32][65], pi[32][65];
  __shared__ float cre_s[32], cim_s[32];
  __shared__ float kt[64];

  float dt = expf(log_dt[lh]);
  if (tid < 32) {
    int n = tid;
    int idx = lh * 32 + n;
    float ar = A_re[idx], ai = A_im[idx];
    float dr = dt * ar, di = dt * ai;
    float er = expf(dr), cd = cosf(di), sd = sinf(di);
    float rr = er * cd, ri = er * sd;
    float sh = sinf(0.5f * di);
    float mr = expm1f(dr) * cd - 2.f * sh * sh;
    float mi = ri;
    float inv = 1.f / (ar * ar + ai * ai);
    float qr = (mr * ar + mi * ai) * inv;
    float qi = (mi * ar - mr * ai) * inv;
    float cre = C_re[idx], cim = C_im[idx];
    cre_s[n] = 2.f * (cre * qr - cim * qi);
    cim_s[n] = 2.f * (cre * qi + cim * qr);
    float xr = 1.f, xi = 0.f;
    for (int k = 0; k < 65; k++) {
      pr[n][k] = xr;
      pi[n][k] = xi;
      float nxr = xr * rr - xi * ri;
      float nxi = xr * ri + xi * rr;
      xr = nxr;
      xi = nxi;
    }
    rT[idx * 2] = pr[n][64];
    rT[idx * 2 + 1] = pi[n][64];
  }
  __syncthreads();
  {
    int d = tid;
    float s = 0.f;
    for (int n = 0; n < 32; n++) s += cre_s[n] * pr[n][d] - cim_s[n] * pi[n][d];
    if (d == 0) s += Dskip[lh];
    kt[d] = s;
  }
  __syncthreads();
  // A_c fragments: [K_toep | W2]
  f16* ac = Afrag_c + (size_t)lh * 8192;
#pragma unroll
  for (int it = 0; it < 16; it++) {
    int ks = it >> 2, rt = it & 3;
    int t = rt * 16 + (tid & 15);
    int kbase = ks * 32 + (tid >> 4) * 8;
    f16x8 v;
#pragma unroll
    for (int j = 0; j < 8; j++) {
      int k = kbase + j;
      float val;
      if (k < 64) {
        val = (t >= k) ? kt[t - k] : 0.f;
      } else {
        int s2 = k - 64;
        int n = s2 >> 1;
        float prr = pr[n][t + 1], pii = pi[n][t + 1];
        val = ((s2 & 1) == 0) ? (cre_s[n] * prr - cim_s[n] * pii)
                              : -(cre_s[n] * pii + cim_s[n] * prr);
      }
      v[j] = (f16)val;
    }
    *(f16x8*)(ac + (size_t)(it * 64 + tid) * 8) = v;
  }
  // A_a fragments (V)
  f16* aa = Afrag_a + (size_t)lh * 4096;
#pragma unroll
  for (int it = 0; it < 8; it++) {
    int ks = it >> 2, rt = it & 3;
    int s2 = rt * 16 + (tid & 15);
    int n = s2 >> 1;
    int kbase = ks * 32 + (tid >> 4) * 8;
    f16x8 v;
#pragma unroll
    for (int j = 0; j < 8; j++) {
      int t = kbase + j;
      v[j] = (f16)(((s2 & 1) == 0) ? pr[n][63 - t] : pi[n][63 - t]);
    }
    *(f16x8*)(aa + (size_t)(it * 64 + tid) * 8) = v;
  }
}

// ---------------------------------------------------------------------------
// K1: fp32 -> fp16 convert (weights)
// ---------------------------------------------------------------------------
__global__ void f32_to_f16_kernel(const float* __restrict__ s, f16* __restrict__ d,
                                  int n) {
  int i = blockIdx.x * 256 + threadIdx.x;
  if (i < n) d[i] = (f16)s[i];
}

// ---------------------------------------------------------------------------
// K1b: Wo fp32 -> MFMA-A-fragment-ordered fp16.
// woF[layer][mt(64)][ks(16)][lane(64)][8] = Wo[mt*16+(lane&15)][ks*32+(lane>>4)*8+j]
// ---------------------------------------------------------------------------
__global__ __launch_bounds__(256) void wo_frag_kernel(const float* __restrict__ Wo,
                                                      f16* __restrict__ woF) {
  int layer = blockIdx.y, mt = blockIdx.x;
  int t = threadIdx.x;
  int lane = t & 63;
  const float* w = Wo + (size_t)layer * 2 * kH * kH;
  f16* dst = woF + ((size_t)layer * 64 + mt) * 8192;
  int row = mt * 16 + (lane & 15);
  int cbase = (lane >> 4) * 8;
#pragma unroll
  for (int it = 0; it < 4; it++) {
    int ks = it * 4 + (t >> 6);
    f16x8 v;
#pragma unroll
    for (int j = 0; j < 8; j++) v[j] = (f16)w[(size_t)row * kH + ks * 32 + cbase + j];
    *(f16x8*)(dst + (size_t)(ks * 64 + lane) * 8) = v;
  }
}

// ---------------------------------------------------------------------------
// K2: (B, L, E) fp32 -> (B, E, L) fp16 transpose (input)
// ---------------------------------------------------------------------------
__global__ __launch_bounds__(256) void transpose_kernel(const float* __restrict__ x,
                                                        f16* __restrict__ u) {
  __shared__ float tile[32][33];
  int b = blockIdx.z;
  int l0 = blockIdx.x * 32, e0 = blockIdx.y * 32;
  int tx = threadIdx.x, ty = threadIdx.y;  // (32, 8)
#pragma unroll
  for (int k = 0; k < 4; k++)
    tile[ty + 8 * k][tx] = x[((size_t)b * kL + (size_t)(l0 + ty + 8 * k)) * kH + e0 + tx];
  __syncthreads();
#pragma unroll
  for (int k = 0; k < 4; k++)
    u[((size_t)b * kH + (size_t)(e0 + ty + 8 * k)) * kL + l0 + tx] =
        (f16)tile[tx][ty + 8 * k];
}

// ---------------------------------------------------------------------------
// K_t16: f16 (B,H,L) -> (B,L,H) transpose, 64x64 LDS tiles.
// ---------------------------------------------------------------------------
__global__ __launch_bounds__(256) void t16_kernel(const f16* __restrict__ y,
                                                  f16* __restrict__ yt) {
  __shared__ f16 tile[64][72];
  int b = blockIdx.z;
  int h0 = blockIdx.y * 64, l0 = blockIdx.x * 64;
  int t = threadIdx.x;
  int row = t >> 3, lc = t & 7;  // 32 rows x 8 col-chunks
#pragma unroll
  for (int r2 = 0; r2 < 2; r2++) {
    int r = row + 32 * r2;
    *(f16x8*)&tile[r][lc * 8] =
        *(const f16x8*)(y + (size_t)(b * kH + h0 + r) * kL + l0 + lc * 8);
  }
  __syncthreads();
  int li = t >> 2, sc = t & 3;  // 64 l-rows x 4 h-chunks (x2 iter)
#pragma unroll
  for (int s2 = 0; s2 < 2; s2++) {
    int s = sc + 4 * s2;
    f16x8 v;
#pragma unroll
    for (int j = 0; j < 8; j++) v[j] = tile[s * 8 + j][li];
    *(f16x8*)(yt + ((size_t)b * kL + l0 + li) * kH + h0 + s * 8) = v;
  }
}

// ---------------------------------------------------------------------------
// K_a: w = V @ u_chunk via MFMA. Output w[b][h][c][64 state-reals] fp16.
// ---------------------------------------------------------------------------
__global__ __launch_bounds__(256) void chunk_w_kernel(
    const f16* __restrict__ u, const f16* __restrict__ Afrag_a,
    f16* __restrict__ wout, int layer) {
  int h = blockIdx.y;
  int lane = threadIdx.x & 63, w = threadIdx.x >> 6;
  int col0 = blockIdx.x * 256 + w * 64;
  const f16* aa = Afrag_a + (size_t)(layer * kH + h) * 4096;
  int k8 = lane >> 4, cl = lane & 15;
  f32x4 acc[4][4] = {};
#pragma unroll
  for (int ks = 0; ks < 2; ks++) {
    f16x8 af[4], bf[4];
#pragma unroll
    for (int rt = 0; rt < 4; rt++)
      af[rt] = *(const f16x8*)(aa + (size_t)((ks * 4 + rt) * 64 + lane) * 8);
#pragma unroll
    for (int ct = 0; ct < 4; ct++) {
      int col = col0 + ct * 16 + cl;
      int b = col >> 4, c = col & 15;
      bf[ct] = *(const f16x8*)(u + (size_t)(b * kH + h) * kL + c * 64 + ks * 32 + k8 * 8);
    }
#pragma unroll
    for (int rt = 0; rt < 4; rt++)
#pragma unroll
      for (int ct = 0; ct < 4; ct++)
        acc[rt][ct] =
            __builtin_amdgcn_mfma_f32_16x16x32_f16(af[rt], bf[ct], acc[rt][ct], 0, 0, 0);
  }
  int q = lane >> 4;
#pragma unroll
  for (int ct = 0; ct < 4; ct++) {
    int col = col0 + ct * 16 + cl;
    int b = col >> 4, c = col & 15;
    f16* wp = wout + ((size_t)(b * kH + h) * kM + c) * 64;
#pragma unroll
    for (int rt = 0; rt < 4; rt++) {
      f16x4 v;
#pragma unroll
      for (int reg = 0; reg < 4; reg++) v[reg] = (f16)acc[rt][ct][reg];
      *(f16x4*)(wp + rt * 16 + q * 4) = v;
    }
  }
}

// ---------------------------------------------------------------------------
// K_b: inter-chunk state scan. S_{c+1} = r^64 * S_c + w_c.
// ---------------------------------------------------------------------------
__global__ __launch_bounds__(256) void chunk_scan_kernel(
    const f16* __restrict__ w, const float* __restrict__ rT,
    f16* __restrict__ S, int layer) {
  int idx = blockIdx.x * 256 + threadIdx.x;  // b*H*32 + h*32 + n
  int n = idx & 31;
  int bh = idx >> 5;
  int h = bh & (kH - 1);
  int lhn = (layer * kH + h) * 32 + n;
  float tr = rT[lhn * 2], ti = rT[lhn * 2 + 1];
  float Sr = 0.f, Si = 0.f;
  const f16* wp = w + (size_t)bh * kM * 64 + 2 * n;
  f16* Sp = S + (size_t)bh * kM * 64 + 2 * n;
#pragma unroll
  for (int c = 0; c < kM; c++) {
    Sp[c * 64] = (f16)Sr;
    Sp[c * 64 + 1] = (f16)Si;
    float wr = (float)wp[c * 64], wi = (float)wp[c * 64 + 1];
    float nSr = fmaf(tr, Sr, fmaf(-ti, Si, wr));
    float nSi = fmaf(tr, Si, fmaf(ti, Sr, wi));
    Sr = nSr;
    Si = nSi;
  }
}

// ---------------------------------------------------------------------------
// K_c: y = [K_toep | W2] @ [u_chunk; S_c] via MFMA, + GELU. Stores (B,H,L)
// coalesced; t16_kernel transposes afterward.
// ---------------------------------------------------------------------------
__global__ __launch_bounds__(256) void chunk_y_kernel(
    const f16* __restrict__ u, const f16* __restrict__ S,
    const f16* __restrict__ Afrag_c, f16* __restrict__ yout, int layer) {
  int h = blockIdx.y;
  int lane = threadIdx.x & 63, w = threadIdx.x >> 6;
  int col0 = blockIdx.x * 256 + w * 64;
  const f16* ac = Afrag_c + (size_t)(layer * kH + h) * 8192;
  int k8 = lane >> 4, cl = lane & 15;
  f32x4 acc[4][4] = {};
#pragma unroll
  for (int ks = 0; ks < 4; ks++) {
    f16x8 af[4], bf[4];
#pragma unroll
    for (int rt = 0; rt < 4; rt++)
      af[rt] = *(const f16x8*)(ac + (size_t)((ks * 4 + rt) * 64 + lane) * 8);
#pragma unroll
    for (int ct = 0; ct < 4; ct++) {
      int col = col0 + ct * 16 + cl;
      int b = col >> 4, c = col & 15;
      if (ks < 2)
        bf[ct] =
            *(const f16x8*)(u + (size_t)(b * kH + h) * kL + c * 64 + ks * 32 + k8 * 8);
      else
        bf[ct] = *(const f16x8*)(S + ((size_t)(b * kH + h) * kM + c) * 64 +
                                 (ks - 2) * 32 + k8 * 8);
    }
#pragma unroll
    for (int rt = 0; rt < 4; rt++)
#pragma unroll
      for (int ct = 0; ct < 4; ct++)
        acc[rt][ct] =
            __builtin_amdgcn_mfma_f32_16x16x32_f16(af[rt], bf[ct], acc[rt][ct], 0, 0, 0);
  }
  int q = lane >> 4;
#pragma unroll
  for (int ct = 0; ct < 4; ct++) {
    int col = col0 + ct * 16 + cl;
    int b = col >> 4, c = col & 15;
    f16* yp = yout + (size_t)(b * kH + h) * kL + c * 64;
#pragma unroll
    for (int rt = 0; rt < 4; rt++) {
      f16x4 v;
#pragma unroll
      for (int reg = 0; reg < 4; reg++) v[reg] = (f16)gelu_tanh(acc[rt][ct][reg]);
      *(f16x4*)(yp + rt * 16 + q * 4) = v;
    }
  }
}

// ---------------------------------------------------------------------------
// K4: GLU GEMM, LDS-free: A-fragments direct from woF (L2-resident),
// B-fragments direct from yt (K-contiguous, 64B-line covered per wave).
// Wave = 32 h (both GLU halves) x 64 l. No barriers.
// grid (4 mg-groups, 512 n-groups); adjacent blocks share B for L2 locality.
// ---------------------------------------------------------------------------
__global__ __launch_bounds__(256) void glu_mfma_kernel(
    const f16* __restrict__ yt,   // (B, L, H)
    const f16* __restrict__ woF,  // fragment-ordered Wo, this layer
    const float* __restrict__ bo, // (2H,)
    f16* __restrict__ uout) {     // (B, H, L)
  int lane = threadIdx.x & 63, w = threadIdx.x >> 6;
  int mg = blockIdx.x * 4 + w;  // 0..15
  int ng = blockIdx.y;          // 0..511
  int b = ng >> 4;
  int l0 = (ng & 15) * 64;
  const f16* ytb = yt + ((size_t)b * kL + l0) * kH;
  int cl = lane & 15, k8 = lane >> 4;
  int mt0 = 2 * mg;  // m-tiles: mt0, mt0+1 (half1), 32+mt0, 32+mt0+1 (half2)
  f32x4 acc[4][4] = {};
#pragma unroll 4
  for (int ks = 0; ks < 16; ks++) {
    f16x8 af[4], bf[4];
#pragma unroll
    for (int i = 0; i < 4; i++) {
      int mt = (i < 2) ? (mt0 + i) : (30 + mt0 + i);  // 32 + mt0 + (i-2)
      af[i] = *(const f16x8*)(woF + (size_t)((mt * 16 + ks) * 64 + lane) * 8);
    }
#pragma unroll
    for (int ct = 0; ct < 4; ct++)
      bf[ct] = *(const f16x8*)(ytb + (size_t)(ct * 16 + cl) * kH + ks * 32 + k8 * 8);
#pragma unroll
    for (int i = 0; i < 4; i++)
#pragma unroll
      for (int ct = 0; ct < 4; ct++)
        acc[i][ct] =
            __builtin_amdgcn_mfma_f32_16x16x32_f16(af[i], bf[ct], acc[i][ct], 0, 0, 0);
  }
  int col = lane & 15, q = lane >> 4;
  f16* ub = uout + (size_t)b * kH * kL;
#pragma unroll
  for (int i = 0; i < 2; i++) {
#pragma unroll
    for (int reg = 0; reg < 4; reg++) {
      int h = (mt0 + i) * 16 + q * 4 + reg;
      float b1 = bo[h], b2 = bo[h + kH];
#pragma unroll
      for (int nt = 0; nt < 4; nt++) {
        float z1 = acc[i][nt][reg] + b1;
        float z2 = acc[i + 2][nt][reg] + b2;
        float sg = 1.f / (1.f + __expf(-z2));
        ub[(size_t)h * kL + l0 + nt * 16 + col] = (f16)(z1 * sg);
      }
    }
  }
}

// ---------------------------------------------------------------------------
// K5: final projection via MFMA f16 (unchanged).
// ---------------------------------------------------------------------------
__global__ __launch_bounds__(256) void final_mfma_kernel(
    const f16* __restrict__ x, const f16* __restrict__ wout,
    const float* __restrict__ bout, float* __restrict__ outp) {
  __shared__ __align__(16) f16 At[16][64][8];
  __shared__ __align__(16) f16 Bt[16][64][8];
  int tid = threadIdx.x;
  int lane = tid & 63, w = tid >> 6;
  int wm = w >> 1, wn = w & 1;
  int lr = lane & 15, lc = lane >> 4;
  int b = blockIdx.z, p0 = blockIdx.y * 128, h0 = blockIdx.x * 128;
  const f16* xb = x + (size_t)b * kH * kL;

  f32x4 acc[4][4] = {};

  const f16* gA[4];
  const f16* gB[4];
#pragma unroll
  for (int i = 0; i < 4; ++i) {
    int st = w * 4 + i, mt = st >> 1, ks = st & 1;
    int prow = p0 + mt * 16 + lr;
    if (prow > kP - 1) prow = kP - 1;
    gA[i] = wout + (size_t)prow * kL + ks * 32 + lc * 8;
    int hrow = h0 + mt * 16 + lr;
    gB[i] = xb + (size_t)hrow * kL + ks * 32 + lc * 8;
  }

  for (int k0 = 0; k0 < kL; k0 += 64) {
#pragma unroll
    for (int i = 0; i < 4; ++i) {
      int st = w * 4 + i;
      llds16(gA[i] + k0, &At[st][0][0]);
      llds16(gB[i] + k0, &Bt[st][0][0]);
    }
    __syncthreads();
#pragma unroll
    for (int ks = 0; ks < 2; ++ks) {
      f16x8 av[4], bv[4];
#pragma unroll
      for (int i = 0; i < 4; ++i)
        av[i] = *(const f16x8*)At[(wm * 4 + i) * 2 + ks][lane];
#pragma unroll
      for (int nt = 0; nt < 4; ++nt)
        bv[nt] = *(const f16x8*)Bt[(wn * 4 + nt) * 2 + ks][lane];
#pragma unroll
      for (int i = 0; i < 4; ++i)
#pragma unroll
        for (int nt = 0; nt < 4; ++nt)
          acc[i][nt] =
              __builtin_amdgcn_mfma_f32_16x16x32_f16(av[i], bv[nt], acc[i][nt], 0, 0, 0);
    }
    __syncthreads();
  }

  int col = lane & 15, q = lane >> 4;
  float* ob = outp + (size_t)b * kP * kH;
#pragma unroll
  for (int i = 0; i < 4; ++i) {
#pragma unroll
    for (int reg = 0; reg < 4; ++reg) {
      int p = p0 + wm * 64 + i * 16 + q * 4 + reg;
      if (p < kP) {
        float bv2 = bout[p];
#pragma unroll
        for (int nt = 0; nt < 4; ++nt)
          ob[(size_t)p * kH + h0 + wn * 64 + nt * 16 + col] = acc[i][nt][reg] + bv2;
      }
    }
  }
}

}  // namespace

extern "C" void kernel_launch(void* const* d_in, const int* in_sizes, int n_in,
                              void* d_out, int out_size, void* d_ws, size_t ws_size,
                              hipStream_t stream) {
  const float* x_enc  = (const float*)d_in[0];
  const float* log_dt = (const float*)d_in[4];
  const float* A_re   = (const float*)d_in[5];
  const float* A_im   = (const float*)d_in[6];
  const float* C_re   = (const float*)d_in[7];
  const float* C_im   = (const float*)d_in[8];
  const float* Dskip  = (const float*)d_in[9];
  const float* Wo     = (const float*)d_in[10];
  const float* bo     = (const float*)d_in[11];
  const float* W_out  = (const float*)d_in[12];
  const float* b_out  = (const float*)d_in[13];
  float* out = (float*)d_out;

  char* wsb = (char*)d_ws;
  f16* u16    = (f16*)(wsb);                   // 32 MB: u (B,H,L)
  f16* ybuf   = (f16*)(wsb + 33554432);        // 32 MB: w, then y (B,H,L)
  f16* S16    = (f16*)(wsb + 67108864);        // 32 MB: S, then yt (B,L,H)
  f16* woF    = (f16*)(wsb + 100663296);       // 3 MB fragment-ordered Wo
  f16* wout16 = (f16*)(wsb + 103809024);       // 672 KB
  f16* afc    = (f16*)(wsb + 104497152);       // 24 MB  [lh][16][64][8]
  f16* afa    = (f16*)(wsb + 129662976);       // 12 MB  [lh][8][64][8]
  float* rT   = (float*)(wsb + 142245888);     // 384 KB [lh][32][2]

  const int nwp = kP * kL;
  f32_to_f16_kernel<<<(nwp + 255) / 256, 256, 0, stream>>>(W_out, wout16, nwp);
  wo_frag_kernel<<<dim3(64, kNL), 256, 0, stream>>>(Wo, woF);

  prep_kernel<<<kNL * kH, 64, 0, stream>>>(log_dt, A_re, A_im, C_re, C_im, Dskip,
                                           afc, afa, rT);

  transpose_kernel<<<dim3(kL / 32, kH / 32, kB), dim3(32, 8), 0, stream>>>(x_enc, u16);

  for (int layer = 0; layer < kNL; layer++) {
    chunk_w_kernel<<<dim3(2, kH), 256, 0, stream>>>(u16, afa, ybuf, layer);
    chunk_scan_kernel<<<kB * kH * kNS / 256, 256, 0, stream>>>(ybuf, rT, S16, layer);
    chunk_y_kernel<<<dim3(2, kH), 256, 0, stream>>>(u16, S16, afc, ybuf, layer);
    t16_kernel<<<dim3(kL / 64, kH / 64, kB), 256, 0, stream>>>(ybuf, S16);
    glu_mfma_kernel<<<dim3(4, 512), 256, 0, stream>>>(
        S16, woF + (size_t)layer * 64 * 8192, bo + (size_t)layer * 2 * kH, u16);
  }

  final_mfma_kernel<<<dim3(kH / 128, 3, kB), 256, 0, stream>>>(u16, wout16, b_out, out);
}

// Round 10
// 613.677 us; speedup vs baseline: 1.0953x; 1.0953x over previous
//
#include <hip/hip_runtime.h>
#include <math.h>

typedef _Float16 f16;
typedef f16 f16x4 __attribute__((ext_vector_type(4)));
typedef f16 f16x8 __attribute__((ext_vector_type(8)));
typedef float f32x4 __attribute__((ext_vector_type(4)));

namespace {

constexpr int kB  = 32;
constexpr int kL  = 1024;
constexpr int kH  = 512;
constexpr int kP  = 336;
constexpr int kNL = 3;
constexpr int kNS = 32;
constexpr int kM  = 16;   // chunks per row (L/64)

// async global->LDS, 16B per lane. LDS dest is wave-uniform base + lane*16.
__device__ __forceinline__ void llds16(const void* g, void* s) {
  __builtin_amdgcn_global_load_lds((const __attribute__((address_space(1))) void*)g,
                                   (__attribute__((address_space(3))) void*)s, 16, 0, 0);
}

__device__ __forceinline__ float gelu_tanh(float y0) {
  float x3 = y0 * y0 * y0;
  float a = 0.7978845608028654f * fmaf(0.044715f, x3, y0);
  float aa = fminf(a, 15.f);
  float ex = __expf(2.f * aa);
  float th = 1.f - 2.f / (ex + 1.f);
  return 0.5f * y0 * (1.f + th);
}

// ---------------------------------------------------------------------------
// K_pre: per (layer,h) build chunked-scan operands (see R6 notes).
// ---------------------------------------------------------------------------
__global__ __launch_bounds__(64) void prep_kernel(
    const float* __restrict__ log_dt, const float* __restrict__ A_re,
    const float* __restrict__ A_im, const float* __restrict__ C_re,
    const float* __restrict__ C_im, const float* __restrict__ Dskip,
    f16* __restrict__ Afrag_c, f16* __restrict__ Afrag_a,
    float* __restrict__ rT) {
  int lh = blockIdx.x;   // layer*H + h
  int tid = threadIdx.x; // 0..63
  __shared__ float pr[32][65], pi[32][65];
  __shared__ float cre_s[32], cim_s[32];
  __shared__ float kt[64];

  float dt = expf(log_dt[lh]);
  if (tid < 32) {
    int n = tid;
    int idx = lh * 32 + n;
    float ar = A_re[idx], ai = A_im[idx];
    float dr = dt * ar, di = dt * ai;
    float er = expf(dr), cd = cosf(di), sd = sinf(di);
    float rr = er * cd, ri = er * sd;
    float sh = sinf(0.5f * di);
    float mr = expm1f(dr) * cd - 2.f * sh * sh;
    float mi = ri;
    float inv = 1.f / (ar * ar + ai * ai);
    float qr = (mr * ar + mi * ai) * inv;
    float qi = (mi * ar - mr * ai) * inv;
    float cre = C_re[idx], cim = C_im[idx];
    cre_s[n] = 2.f * (cre * qr - cim * qi);
    cim_s[n] = 2.f * (cre * qi + cim * qr);
    float xr = 1.f, xi = 0.f;
    for (int k = 0; k < 65; k++) {
      pr[n][k] = xr;
      pi[n][k] = xi;
      float nxr = xr * rr - xi * ri;
      float nxi = xr * ri + xi * rr;
      xr = nxr;
      xi = nxi;
    }
    rT[idx * 2] = pr[n][64];
    rT[idx * 2 + 1] = pi[n][64];
  }
  __syncthreads();
  {
    int d = tid;
    float s = 0.f;
    for (int n = 0; n < 32; n++) s += cre_s[n] * pr[n][d] - cim_s[n] * pi[n][d];
    if (d == 0) s += Dskip[lh];
    kt[d] = s;
  }
  __syncthreads();
  // A_c fragments: [K_toep | W2]
  f16* ac = Afrag_c + (size_t)lh * 8192;
#pragma unroll
  for (int it = 0; it < 16; it++) {
    int ks = it >> 2, rt = it & 3;
    int t = rt * 16 + (tid & 15);
    int kbase = ks * 32 + (tid >> 4) * 8;
    f16x8 v;
#pragma unroll
    for (int j = 0; j < 8; j++) {
      int k = kbase + j;
      float val;
      if (k < 64) {
        val = (t >= k) ? kt[t - k] : 0.f;
      } else {
        int s2 = k - 64;
        int n = s2 >> 1;
        float prr = pr[n][t + 1], pii = pi[n][t + 1];
        val = ((s2 & 1) == 0) ? (cre_s[n] * prr - cim_s[n] * pii)
                              : -(cre_s[n] * pii + cim_s[n] * prr);
      }
      v[j] = (f16)val;
    }
    *(f16x8*)(ac + (size_t)(it * 64 + tid) * 8) = v;
  }
  // A_a fragments (V)
  f16* aa = Afrag_a + (size_t)lh * 4096;
#pragma unroll
  for (int it = 0; it < 8; it++) {
    int ks = it >> 2, rt = it & 3;
    int s2 = rt * 16 + (tid & 15);
    int n = s2 >> 1;
    int kbase = ks * 32 + (tid >> 4) * 8;
    f16x8 v;
#pragma unroll
    for (int j = 0; j < 8; j++) {
      int t = kbase + j;
      v[j] = (f16)(((s2 & 1) == 0) ? pr[n][63 - t] : pi[n][63 - t]);
    }
    *(f16x8*)(aa + (size_t)(it * 64 + tid) * 8) = v;
  }
}

// ---------------------------------------------------------------------------
// K1: fp32 -> fp16 convert (weights)
// ---------------------------------------------------------------------------
__global__ void f32_to_f16_kernel(const float* __restrict__ s, f16* __restrict__ d,
                                  int n) {
  int i = blockIdx.x * 256 + threadIdx.x;
  if (i < n) d[i] = (f16)s[i];
}

// ---------------------------------------------------------------------------
// K2: (B, L, E) fp32 -> (B, E, L) fp16 transpose (input)
// ---------------------------------------------------------------------------
__global__ __launch_bounds__(256) void transpose_kernel(const float* __restrict__ x,
                                                        f16* __restrict__ u) {
  __shared__ float tile[32][33];
  int b = blockIdx.z;
  int l0 = blockIdx.x * 32, e0 = blockIdx.y * 32;
  int tx = threadIdx.x, ty = threadIdx.y;  // (32, 8)
#pragma unroll
  for (int k = 0; k < 4; k++)
    tile[ty + 8 * k][tx] = x[((size_t)b * kL + (size_t)(l0 + ty + 8 * k)) * kH + e0 + tx];
  __syncthreads();
#pragma unroll
  for (int k = 0; k < 4; k++)
    u[((size_t)b * kH + (size_t)(e0 + ty + 8 * k)) * kL + l0 + tx] =
        (f16)tile[tx][ty + 8 * k];
}

// ---------------------------------------------------------------------------
// K_t16: f16 (B,H,L) -> (B,L,H) transpose, 64x64 LDS tiles.
// ---------------------------------------------------------------------------
__global__ __launch_bounds__(256) void t16_kernel(const f16* __restrict__ y,
                                                  f16* __restrict__ yt) {
  __shared__ f16 tile[64][72];
  int b = blockIdx.z;
  int h0 = blockIdx.y * 64, l0 = blockIdx.x * 64;
  int t = threadIdx.x;
  int row = t >> 3, lc = t & 7;  // 32 rows x 8 col-chunks
#pragma unroll
  for (int r2 = 0; r2 < 2; r2++) {
    int r = row + 32 * r2;
    *(f16x8*)&tile[r][lc * 8] =
        *(const f16x8*)(y + (size_t)(b * kH + h0 + r) * kL + l0 + lc * 8);
  }
  __syncthreads();
  int li = t >> 2, sc = t & 3;  // 64 l-rows x 4 h-chunks (x2 iter)
#pragma unroll
  for (int s2 = 0; s2 < 2; s2++) {
    int s = sc + 4 * s2;
    f16x8 v;
#pragma unroll
    for (int j = 0; j < 8; j++) v[j] = tile[s * 8 + j][li];
    *(f16x8*)(yt + ((size_t)b * kL + l0 + li) * kH + h0 + s * 8) = v;
  }
}

// ---------------------------------------------------------------------------
// K_wy: FUSED chunk pipeline. Per wave (64 cols = 4 b's x 16 chunks, c=cl):
//  A) w = V@u via MFMA (u fragments kept in regs)
//  B) inter-chunk scan = Hillis-Steele across cl lanes (shfl_up width 16),
//     multipliers T^(2^d) by repeated squaring of rT
//  C) exclusive shift + LDS bounce to B-fragment layout
//  D) y = [Ktoep|W2]@[u;S] via MFMA + GELU, coalesced (B,H,L) store.
// Replaces chunk_w + chunk_scan + chunk_y (saves 128 MB/layer w/S traffic).
// ---------------------------------------------------------------------------
__global__ __launch_bounds__(256) void chunk_wy_kernel(
    const f16* __restrict__ u, const f16* __restrict__ Afrag_a,
    const f16* __restrict__ Afrag_c, const float* __restrict__ rT,
    f16* __restrict__ yout, int layer) {
  __shared__ __align__(16) f16 Sl[4][4][16][72];  // [wave][ct][c][row(64)+pad]
  int h = blockIdx.y;
  int lane = threadIdx.x & 63, w = threadIdx.x >> 6;
  int col0 = blockIdx.x * 256 + w * 64;
  const f16* aa = Afrag_a + (size_t)(layer * kH + h) * 4096;
  const f16* ac = Afrag_c + (size_t)(layer * kH + h) * 8192;
  int k8 = lane >> 4, cl = lane & 15;  // k8 == q (C-layout quad)

  // ---- Phase A: w = V @ u
  f16x8 uf[4][2];
  f32x4 acc[4][4] = {};
#pragma unroll
  for (int ks = 0; ks < 2; ks++) {
    f16x8 af[4];
#pragma unroll
    for (int rt = 0; rt < 4; rt++)
      af[rt] = *(const f16x8*)(aa + (size_t)((ks * 4 + rt) * 64 + lane) * 8);
#pragma unroll
    for (int ct = 0; ct < 4; ct++) {
      int col = col0 + ct * 16 + cl;
      int b = col >> 4, c = col & 15;
      uf[ct][ks] =
          *(const f16x8*)(u + (size_t)(b * kH + h) * kL + c * 64 + ks * 32 + k8 * 8);
    }
#pragma unroll
    for (int rt = 0; rt < 4; rt++)
#pragma unroll
      for (int ct = 0; ct < 4; ct++)
        acc[rt][ct] =
            __builtin_amdgcn_mfma_f32_16x16x32_f16(af[rt], uf[ct][ks], acc[rt][ct], 0, 0, 0);
  }

  // ---- Phase B: prefix scan across chunks (cl lanes), per rt
  int lhb = (layer * kH + h) * 32;
#pragma unroll
  for (int rt = 0; rt < 4; rt++) {
    // rT for the two complex states this lane holds in acc[rt][*]
    int n0 = rt * 8 + k8 * 2;
    float t0r = rT[(lhb + n0) * 2], t0i = rT[(lhb + n0) * 2 + 1];
    float t1r = rT[(lhb + n0 + 1) * 2], t1i = rT[(lhb + n0 + 1) * 2 + 1];
#pragma unroll
    for (int d = 0; d < 4; d++) {
      int dist = 1 << d;
#pragma unroll
      for (int ct = 0; ct < 4; ct++) {
        float r0 = __shfl_up(acc[rt][ct][0], dist, 16);
        float i0 = __shfl_up(acc[rt][ct][1], dist, 16);
        float r1 = __shfl_up(acc[rt][ct][2], dist, 16);
        float i1 = __shfl_up(acc[rt][ct][3], dist, 16);
        if (cl >= dist) {
          acc[rt][ct][0] = fmaf(t0r, r0, fmaf(-t0i, i0, acc[rt][ct][0]));
          acc[rt][ct][1] = fmaf(t0r, i0, fmaf(t0i, r0, acc[rt][ct][1]));
          acc[rt][ct][2] = fmaf(t1r, r1, fmaf(-t1i, i1, acc[rt][ct][2]));
          acc[rt][ct][3] = fmaf(t1r, i1, fmaf(t1i, r1, acc[rt][ct][3]));
        }
      }
      // square T -> T^(2^(d+1))
      float s0r = t0r * t0r - t0i * t0i, s0i = 2.f * t0r * t0i;
      float s1r = t1r * t1r - t1i * t1i, s1i = 2.f * t1r * t1i;
      t0r = s0r; t0i = s0i; t1r = s1r; t1i = s1i;
    }
  }

  // ---- Phase C: exclusive shift, write S (f16) to LDS in row-major tile
#pragma unroll
  for (int rt = 0; rt < 4; rt++)
#pragma unroll
    for (int ct = 0; ct < 4; ct++) {
      f16x4 v;
#pragma unroll
      for (int reg = 0; reg < 4; reg++) {
        float e = __shfl_up(acc[rt][ct][reg], 1, 16);
        v[reg] = (f16)((cl == 0) ? 0.f : e);
      }
      *(f16x4*)&Sl[w][ct][cl][rt * 16 + k8 * 4] = v;
    }
  __syncthreads();

  // ---- Phase D: y = [Ktoep | W2] @ [u; S]
  f32x4 accD[4][4] = {};
#pragma unroll
  for (int ks = 0; ks < 4; ks++) {
    f16x8 af[4], bf[4];
#pragma unroll
    for (int rt = 0; rt < 4; rt++)
      af[rt] = *(const f16x8*)(ac + (size_t)((ks * 4 + rt) * 64 + lane) * 8);
#pragma unroll
    for (int ct = 0; ct < 4; ct++) {
      if (ks < 2)
        bf[ct] = uf[ct][ks];
      else
        bf[ct] = *(const f16x8*)&Sl[w][ct][cl][(ks - 2) * 32 + k8 * 8];
    }
#pragma unroll
    for (int rt = 0; rt < 4; rt++)
#pragma unroll
      for (int ct = 0; ct < 4; ct++)
        accD[rt][ct] =
            __builtin_amdgcn_mfma_f32_16x16x32_f16(af[rt], bf[ct], accD[rt][ct], 0, 0, 0);
  }

  // ---- epilogue: GELU + coalesced store (B,H,L)
#pragma unroll
  for (int ct = 0; ct < 4; ct++) {
    int col = col0 + ct * 16 + cl;
    int b = col >> 4, c = col & 15;
    f16* yp = yout + (size_t)(b * kH + h) * kL + c * 64;
#pragma unroll
    for (int rt = 0; rt < 4; rt++) {
      f16x4 v;
#pragma unroll
      for (int reg = 0; reg < 4; reg++) v[reg] = (f16)gelu_tanh(accD[rt][ct][reg]);
      *(f16x4*)(yp + rt * 16 + k8 * 4) = v;
    }
  }
}

// ---------------------------------------------------------------------------
// K4: GLU GEMM via MFMA f16 (R7 version: LDS staging via global_load_lds).
// ---------------------------------------------------------------------------
__global__ __launch_bounds__(256) void glu_mfma_kernel(
    const f16* __restrict__ yt,    // (B, L, H)
    const f16* __restrict__ wo,    // (2H, H) this layer
    const float* __restrict__ bo,  // (2H,)
    f16* __restrict__ uout) {      // (B, H, L)
  __shared__ __align__(16) f16 At[16][64][8];
  __shared__ __align__(16) f16 Bt[16][64][8];
  int tid = threadIdx.x;
  int lane = tid & 63, w = tid >> 6;
  int wm = w >> 1, wn = w & 1;
  int lr = lane & 15, lc = lane >> 4;
  int b = blockIdx.z, h0 = blockIdx.y * 64, l0 = blockIdx.x * 128;
  const f16* ytb = yt + (size_t)b * kL * kH;

  f32x4 acc[4][4] = {};

  const f16* gA[4];
  const f16* gB[4];
#pragma unroll
  for (int i = 0; i < 4; ++i) {
    int st = w * 4 + i, mt = st >> 1, ks = st & 1;
    int row = mt * 16 + lr;
    int hrow = (row < 64) ? (h0 + row) : (448 + h0 + row);
    gA[i] = wo + (size_t)hrow * kH + ks * 32 + lc * 8;
    int lrow = l0 + mt * 16 + lr;
    gB[i] = ytb + (size_t)lrow * kH + ks * 32 + lc * 8;
  }

  for (int k0 = 0; k0 < kH; k0 += 64) {
#pragma unroll
    for (int i = 0; i < 4; ++i) {
      int st = w * 4 + i;
      llds16(gA[i] + k0, &At[st][0][0]);
      llds16(gB[i] + k0, &Bt[st][0][0]);
    }
    __syncthreads();
#pragma unroll
    for (int ks = 0; ks < 2; ++ks) {
      f16x8 av[4], bv[4];
      av[0] = *(const f16x8*)At[(2 * wm + 0) * 2 + ks][lane];
      av[1] = *(const f16x8*)At[(2 * wm + 1) * 2 + ks][lane];
      av[2] = *(const f16x8*)At[(2 * wm + 4) * 2 + ks][lane];
      av[3] = *(const f16x8*)At[(2 * wm + 5) * 2 + ks][lane];
#pragma unroll
      for (int nt = 0; nt < 4; ++nt)
        bv[nt] = *(const f16x8*)Bt[(wn * 4 + nt) * 2 + ks][lane];
#pragma unroll
      for (int i = 0; i < 4; ++i)
#pragma unroll
        for (int nt = 0; nt < 4; ++nt)
          acc[i][nt] =
              __builtin_amdgcn_mfma_f32_16x16x32_f16(av[i], bv[nt], acc[i][nt], 0, 0, 0);
    }
    __syncthreads();
  }

  int col = lane & 15, q = lane >> 4;
  f16* ub = uout + (size_t)b * kH * kL;
#pragma unroll
  for (int i = 0; i < 2; ++i) {
#pragma unroll
    for (int reg = 0; reg < 4; ++reg) {
      int h = h0 + wm * 32 + i * 16 + q * 4 + reg;
      float b1 = bo[h], b2 = bo[h + kH];
#pragma unroll
      for (int nt = 0; nt < 4; ++nt) {
        float z1 = acc[i][nt][reg] + b1;
        float z2 = acc[i + 2][nt][reg] + b2;
        float sg = 1.f / (1.f + __expf(-z2));
        ub[(size_t)h * kL + l0 + wn * 64 + nt * 16 + col] = (f16)(z1 * sg);
      }
    }
  }
}

// ---------------------------------------------------------------------------
// K5: final projection via MFMA f16 (unchanged).
// ---------------------------------------------------------------------------
__global__ __launch_bounds__(256) void final_mfma_kernel(
    const f16* __restrict__ x, const f16* __restrict__ wout,
    const float* __restrict__ bout, float* __restrict__ outp) {
  __shared__ __align__(16) f16 At[16][64][8];
  __shared__ __align__(16) f16 Bt[16][64][8];
  int tid = threadIdx.x;
  int lane = tid & 63, w = tid >> 6;
  int wm = w >> 1, wn = w & 1;
  int lr = lane & 15, lc = lane >> 4;
  int b = blockIdx.z, p0 = blockIdx.y * 128, h0 = blockIdx.x * 128;
  const f16* xb = x + (size_t)b * kH * kL;

  f32x4 acc[4][4] = {};

  const f16* gA[4];
  const f16* gB[4];
#pragma unroll
  for (int i = 0; i < 4; ++i) {
    int st = w * 4 + i, mt = st >> 1, ks = st & 1;
    int prow = p0 + mt * 16 + lr;
    if (prow > kP - 1) prow = kP - 1;
    gA[i] = wout + (size_t)prow * kL + ks * 32 + lc * 8;
    int hrow = h0 + mt * 16 + lr;
    gB[i] = xb + (size_t)hrow * kL + ks * 32 + lc * 8;
  }

  for (int k0 = 0; k0 < kL; k0 += 64) {
#pragma unroll
    for (int i = 0; i < 4; ++i) {
      int st = w * 4 + i;
      llds16(gA[i] + k0, &At[st][0][0]);
      llds16(gB[i] + k0, &Bt[st][0][0]);
    }
    __syncthreads();
#pragma unroll
    for (int ks = 0; ks < 2; ++ks) {
      f16x8 av[4], bv[4];
#pragma unroll
      for (int i = 0; i < 4; ++i)
        av[i] = *(const f16x8*)At[(wm * 4 + i) * 2 + ks][lane];
#pragma unroll
      for (int nt = 0; nt < 4; ++nt)
        bv[nt] = *(const f16x8*)Bt[(wn * 4 + nt) * 2 + ks][lane];
#pragma unroll
      for (int i = 0; i < 4; ++i)
#pragma unroll
        for (int nt = 0; nt < 4; ++nt)
          acc[i][nt] =
              __builtin_amdgcn_mfma_f32_16x16x32_f16(av[i], bv[nt], acc[i][nt], 0, 0, 0);
    }
    __syncthreads();
  }

  int col = lane & 15, q = lane >> 4;
  float* ob = outp + (size_t)b * kP * kH;
#pragma unroll
  for (int i = 0; i < 4; ++i) {
#pragma unroll
    for (int reg = 0; reg < 4; ++reg) {
      int p = p0 + wm * 64 + i * 16 + q * 4 + reg;
      if (p < kP) {
        float bv2 = bout[p];
#pragma unroll
        for (int nt = 0; nt < 4; ++nt)
          ob[(size_t)p * kH + h0 + wn * 64 + nt * 16 + col] = acc[i][nt][reg] + bv2;
      }
    }
  }
}

}  // namespace

extern "C" void kernel_launch(void* const* d_in, const int* in_sizes, int n_in,
                              void* d_out, int out_size, void* d_ws, size_t ws_size,
                              hipStream_t stream) {
  const float* x_enc  = (const float*)d_in[0];
  const float* log_dt = (const float*)d_in[4];
  const float* A_re   = (const float*)d_in[5];
  const float* A_im   = (const float*)d_in[6];
  const float* C_re   = (const float*)d_in[7];
  const float* C_im   = (const float*)d_in[8];
  const float* Dskip  = (const float*)d_in[9];
  const float* Wo     = (const float*)d_in[10];
  const float* bo     = (const float*)d_in[11];
  const float* W_out  = (const float*)d_in[12];
  const float* b_out  = (const float*)d_in[13];
  float* out = (float*)d_out;

  char* wsb = (char*)d_ws;
  f16* u16    = (f16*)(wsb);                   // 32 MB: u (B,H,L)
  f16* ybuf   = (f16*)(wsb + 33554432);        // 32 MB: y (B,H,L)
  f16* S16    = (f16*)(wsb + 67108864);        // 32 MB: yt (B,L,H)
  f16* wo16   = (f16*)(wsb + 100663296);       // 3 MB  (NL,2H,H)
  f16* wout16 = (f16*)(wsb + 103809024);       // 672 KB
  f16* afc    = (f16*)(wsb + 104497152);       // 24 MB  [lh][16][64][8]
  f16* afa    = (f16*)(wsb + 129662976);       // 12 MB  [lh][8][64][8]
  float* rT   = (float*)(wsb + 142245888);     // 384 KB [lh][32][2]

  const int nwo = kNL * 2 * kH * kH;
  const int nwp = kP * kL;
  f32_to_f16_kernel<<<(nwo + 255) / 256, 256, 0, stream>>>(Wo, wo16, nwo);
  f32_to_f16_kernel<<<(nwp + 255) / 256, 256, 0, stream>>>(W_out, wout16, nwp);

  prep_kernel<<<kNL * kH, 64, 0, stream>>>(log_dt, A_re, A_im, C_re, C_im, Dskip,
                                           afc, afa, rT);

  transpose_kernel<<<dim3(kL / 32, kH / 32, kB), dim3(32, 8), 0, stream>>>(x_enc, u16);

  for (int layer = 0; layer < kNL; layer++) {
    chunk_wy_kernel<<<dim3(2, kH), 256, 0, stream>>>(u16, afa, afc, rT, ybuf, layer);
    t16_kernel<<<dim3(kL / 64, kH / 64, kB), 256, 0, stream>>>(ybuf, S16);
    glu_mfma_kernel<<<dim3(kL / 128, kH / 64, kB), 256, 0, stream>>>(
        S16, wo16 + (size_t)layer * 2 * kH * kH, bo + (size_t)layer * 2 * kH, u16);
  }

  final_mfma_kernel<<<dim3(kH / 128, 3, kB), 256, 0, stream>>>(u16, wout16, b_out, out);
}

// Round 11
// 568.032 us; speedup vs baseline: 1.1834x; 1.0804x over previous
//
#include <hip/hip_runtime.h>
#include <math.h>

typedef _Float16 f16;
typedef f16 f16x4 __attribute__((ext_vector_type(4)));
typedef f16 f16x8 __attribute__((ext_vector_type(8)));
typedef float f32x4 __attribute__((ext_vector_type(4)));

namespace {

constexpr int kB  = 32;
constexpr int kL  = 1024;
constexpr int kH  = 512;
constexpr int kP  = 336;
constexpr int kNL = 3;
constexpr int kNS = 32;
constexpr int kM  = 16;   // chunks per row (L/64)

// async global->LDS, 16B per lane. LDS dest is wave-uniform base + lane*16.
__device__ __forceinline__ void llds16(const void* g, void* s) {
  __builtin_amdgcn_global_load_lds((const __attribute__((address_space(1))) void*)g,
                                   (__attribute__((address_space(3))) void*)s, 16, 0, 0);
}

__device__ __forceinline__ float gelu_tanh(float y0) {
  float x3 = y0 * y0 * y0;
  float a = 0.7978845608028654f * fmaf(0.044715f, x3, y0);
  float aa = fminf(a, 15.f);
  float ex = __expf(2.f * aa);
  float th = 1.f - 2.f / (ex + 1.f);
  return 0.5f * y0 * (1.f + th);
}

// ---------------------------------------------------------------------------
// K_pre: per (layer,h) build chunked-scan operands (see R6 notes).
// ---------------------------------------------------------------------------
__global__ __launch_bounds__(64) void prep_kernel(
    const float* __restrict__ log_dt, const float* __restrict__ A_re,
    const float* __restrict__ A_im, const float* __restrict__ C_re,
    const float* __restrict__ C_im, const float* __restrict__ Dskip,
    f16* __restrict__ Afrag_c, f16* __restrict__ Afrag_a,
    float* __restrict__ rT) {
  int lh = blockIdx.x;   // layer*H + h
  int tid = threadIdx.x; // 0..63
  __shared__ float pr[32][65], pi[32][65];
  __shared__ float cre_s[32], cim_s[32];
  __shared__ float kt[64];

  float dt = expf(log_dt[lh]);
  if (tid < 32) {
    int n = tid;
    int idx = lh * 32 + n;
    float ar = A_re[idx], ai = A_im[idx];
    float dr = dt * ar, di = dt * ai;
    float er = expf(dr), cd = cosf(di), sd = sinf(di);
    float rr = er * cd, ri = er * sd;
    float sh = sinf(0.5f * di);
    float mr = expm1f(dr) * cd - 2.f * sh * sh;
    float mi = ri;
    float inv = 1.f / (ar * ar + ai * ai);
    float qr = (mr * ar + mi * ai) * inv;
    float qi = (mi * ar - mr * ai) * inv;
    float cre = C_re[idx], cim = C_im[idx];
    cre_s[n] = 2.f * (cre * qr - cim * qi);
    cim_s[n] = 2.f * (cre * qi + cim * qr);
    float xr = 1.f, xi = 0.f;
    for (int k = 0; k < 65; k++) {
      pr[n][k] = xr;
      pi[n][k] = xi;
      float nxr = xr * rr - xi * ri;
      float nxi = xr * ri + xi * rr;
      xr = nxr;
      xi = nxi;
    }
    rT[idx * 2] = pr[n][64];
    rT[idx * 2 + 1] = pi[n][64];
  }
  __syncthreads();
  {
    int d = tid;
    float s = 0.f;
    for (int n = 0; n < 32; n++) s += cre_s[n] * pr[n][d] - cim_s[n] * pi[n][d];
    if (d == 0) s += Dskip[lh];
    kt[d] = s;
  }
  __syncthreads();
  // A_c fragments: [K_toep | W2]
  f16* ac = Afrag_c + (size_t)lh * 8192;
#pragma unroll
  for (int it = 0; it < 16; it++) {
    int ks = it >> 2, rt = it & 3;
    int t = rt * 16 + (tid & 15);
    int kbase = ks * 32 + (tid >> 4) * 8;
    f16x8 v;
#pragma unroll
    for (int j = 0; j < 8; j++) {
      int k = kbase + j;
      float val;
      if (k < 64) {
        val = (t >= k) ? kt[t - k] : 0.f;
      } else {
        int s2 = k - 64;
        int n = s2 >> 1;
        float prr = pr[n][t + 1], pii = pi[n][t + 1];
        val = ((s2 & 1) == 0) ? (cre_s[n] * prr - cim_s[n] * pii)
                              : -(cre_s[n] * pii + cim_s[n] * prr);
      }
      v[j] = (f16)val;
    }
    *(f16x8*)(ac + (size_t)(it * 64 + tid) * 8) = v;
  }
  // A_a fragments (V)
  f16* aa = Afrag_a + (size_t)lh * 4096;
#pragma unroll
  for (int it = 0; it < 8; it++) {
    int ks = it >> 2, rt = it & 3;
    int s2 = rt * 16 + (tid & 15);
    int n = s2 >> 1;
    int kbase = ks * 32 + (tid >> 4) * 8;
    f16x8 v;
#pragma unroll
    for (int j = 0; j < 8; j++) {
      int t = kbase + j;
      v[j] = (f16)(((s2 & 1) == 0) ? pr[n][63 - t] : pi[n][63 - t]);
    }
    *(f16x8*)(aa + (size_t)(it * 64 + tid) * 8) = v;
  }
}

// ---------------------------------------------------------------------------
// K1: fp32 -> fp16 convert (weights)
// ---------------------------------------------------------------------------
__global__ void f32_to_f16_kernel(const float* __restrict__ s, f16* __restrict__ d,
                                  int n) {
  int i = blockIdx.x * 256 + threadIdx.x;
  if (i < n) d[i] = (f16)s[i];
}

// ---------------------------------------------------------------------------
// K1b: Wo fp32 -> MFMA-A-fragment-ordered fp16 (verified in R9).
// woF[layer][mt(64)][ks(16)][lane(64)][8] = Wo[mt*16+(lane&15)][ks*32+(lane>>4)*8+j]
// ---------------------------------------------------------------------------
__global__ __launch_bounds__(256) void wo_frag_kernel(const float* __restrict__ Wo,
                                                      f16* __restrict__ woF) {
  int layer = blockIdx.y, mt = blockIdx.x;
  int t = threadIdx.x;
  int lane = t & 63;
  const float* w = Wo + (size_t)layer * 2 * kH * kH;
  f16* dst = woF + ((size_t)layer * 64 + mt) * 8192;
  int row = mt * 16 + (lane & 15);
  int cbase = (lane >> 4) * 8;
#pragma unroll
  for (int it = 0; it < 4; it++) {
    int ks = it * 4 + (t >> 6);
    f16x8 v;
#pragma unroll
    for (int j = 0; j < 8; j++) v[j] = (f16)w[(size_t)row * kH + ks * 32 + cbase + j];
    *(f16x8*)(dst + (size_t)(ks * 64 + lane) * 8) = v;
  }
}

// ---------------------------------------------------------------------------
// K2: (B, L, E) fp32 -> (B, E, L) fp16 transpose (input)
// ---------------------------------------------------------------------------
__global__ __launch_bounds__(256) void transpose_kernel(const float* __restrict__ x,
                                                        f16* __restrict__ u) {
  __shared__ float tile[32][33];
  int b = blockIdx.z;
  int l0 = blockIdx.x * 32, e0 = blockIdx.y * 32;
  int tx = threadIdx.x, ty = threadIdx.y;  // (32, 8)
#pragma unroll
  for (int k = 0; k < 4; k++)
    tile[ty + 8 * k][tx] = x[((size_t)b * kL + (size_t)(l0 + ty + 8 * k)) * kH + e0 + tx];
  __syncthreads();
#pragma unroll
  for (int k = 0; k < 4; k++)
    u[((size_t)b * kH + (size_t)(e0 + ty + 8 * k)) * kL + l0 + tx] =
        (f16)tile[tx][ty + 8 * k];
}

// ---------------------------------------------------------------------------
// K_t16: f16 (B,H,L) -> (B,L,H) transpose, 64x64 LDS tiles.
// ---------------------------------------------------------------------------
__global__ __launch_bounds__(256) void t16_kernel(const f16* __restrict__ y,
                                                  f16* __restrict__ yt) {
  __shared__ f16 tile[64][72];
  int b = blockIdx.z;
  int h0 = blockIdx.y * 64, l0 = blockIdx.x * 64;
  int t = threadIdx.x;
  int row = t >> 3, lc = t & 7;  // 32 rows x 8 col-chunks
#pragma unroll
  for (int r2 = 0; r2 < 2; r2++) {
    int r = row + 32 * r2;
    *(f16x8*)&tile[r][lc * 8] =
        *(const f16x8*)(y + (size_t)(b * kH + h0 + r) * kL + l0 + lc * 8);
  }
  __syncthreads();
  int li = t >> 2, sc = t & 3;  // 64 l-rows x 4 h-chunks (x2 iter)
#pragma unroll
  for (int s2 = 0; s2 < 2; s2++) {
    int s = sc + 4 * s2;
    f16x8 v;
#pragma unroll
    for (int j = 0; j < 8; j++) v[j] = tile[s * 8 + j][li];
    *(f16x8*)(yt + ((size_t)b * kL + l0 + li) * kH + h0 + s * 8) = v;
  }
}

// ---------------------------------------------------------------------------
// K_wy: FUSED chunk pipeline (unchanged from R10).
// ---------------------------------------------------------------------------
__global__ __launch_bounds__(256) void chunk_wy_kernel(
    const f16* __restrict__ u, const f16* __restrict__ Afrag_a,
    const f16* __restrict__ Afrag_c, const float* __restrict__ rT,
    f16* __restrict__ yout, int layer) {
  __shared__ __align__(16) f16 Sl[4][4][16][72];  // [wave][ct][c][row(64)+pad]
  int h = blockIdx.y;
  int lane = threadIdx.x & 63, w = threadIdx.x >> 6;
  int col0 = blockIdx.x * 256 + w * 64;
  const f16* aa = Afrag_a + (size_t)(layer * kH + h) * 4096;
  const f16* ac = Afrag_c + (size_t)(layer * kH + h) * 8192;
  int k8 = lane >> 4, cl = lane & 15;  // k8 == q (C-layout quad)

  // ---- Phase A: w = V @ u
  f16x8 uf[4][2];
  f32x4 acc[4][4] = {};
#pragma unroll
  for (int ks = 0; ks < 2; ks++) {
    f16x8 af[4];
#pragma unroll
    for (int rt = 0; rt < 4; rt++)
      af[rt] = *(const f16x8*)(aa + (size_t)((ks * 4 + rt) * 64 + lane) * 8);
#pragma unroll
    for (int ct = 0; ct < 4; ct++) {
      int col = col0 + ct * 16 + cl;
      int b = col >> 4, c = col & 15;
      uf[ct][ks] =
          *(const f16x8*)(u + (size_t)(b * kH + h) * kL + c * 64 + ks * 32 + k8 * 8);
    }
#pragma unroll
    for (int rt = 0; rt < 4; rt++)
#pragma unroll
      for (int ct = 0; ct < 4; ct++)
        acc[rt][ct] =
            __builtin_amdgcn_mfma_f32_16x16x32_f16(af[rt], uf[ct][ks], acc[rt][ct], 0, 0, 0);
  }

  // ---- Phase B: prefix scan across chunks (cl lanes), per rt
  int lhb = (layer * kH + h) * 32;
#pragma unroll
  for (int rt = 0; rt < 4; rt++) {
    int n0 = rt * 8 + k8 * 2;
    float t0r = rT[(lhb + n0) * 2], t0i = rT[(lhb + n0) * 2 + 1];
    float t1r = rT[(lhb + n0 + 1) * 2], t1i = rT[(lhb + n0 + 1) * 2 + 1];
#pragma unroll
    for (int d = 0; d < 4; d++) {
      int dist = 1 << d;
#pragma unroll
      for (int ct = 0; ct < 4; ct++) {
        float r0 = __shfl_up(acc[rt][ct][0], dist, 16);
        float i0 = __shfl_up(acc[rt][ct][1], dist, 16);
        float r1 = __shfl_up(acc[rt][ct][2], dist, 16);
        float i1 = __shfl_up(acc[rt][ct][3], dist, 16);
        if (cl >= dist) {
          acc[rt][ct][0] = fmaf(t0r, r0, fmaf(-t0i, i0, acc[rt][ct][0]));
          acc[rt][ct][1] = fmaf(t0r, i0, fmaf(t0i, r0, acc[rt][ct][1]));
          acc[rt][ct][2] = fmaf(t1r, r1, fmaf(-t1i, i1, acc[rt][ct][2]));
          acc[rt][ct][3] = fmaf(t1r, i1, fmaf(t1i, r1, acc[rt][ct][3]));
        }
      }
      float s0r = t0r * t0r - t0i * t0i, s0i = 2.f * t0r * t0i;
      float s1r = t1r * t1r - t1i * t1i, s1i = 2.f * t1r * t1i;
      t0r = s0r; t0i = s0i; t1r = s1r; t1i = s1i;
    }
  }

  // ---- Phase C: exclusive shift, write S (f16) to LDS
#pragma unroll
  for (int rt = 0; rt < 4; rt++)
#pragma unroll
    for (int ct = 0; ct < 4; ct++) {
      f16x4 v;
#pragma unroll
      for (int reg = 0; reg < 4; reg++) {
        float e = __shfl_up(acc[rt][ct][reg], 1, 16);
        v[reg] = (f16)((cl == 0) ? 0.f : e);
      }
      *(f16x4*)&Sl[w][ct][cl][rt * 16 + k8 * 4] = v;
    }
  __syncthreads();

  // ---- Phase D: y = [Ktoep | W2] @ [u; S]
  f32x4 accD[4][4] = {};
#pragma unroll
  for (int ks = 0; ks < 4; ks++) {
    f16x8 af[4], bf[4];
#pragma unroll
    for (int rt = 0; rt < 4; rt++)
      af[rt] = *(const f16x8*)(ac + (size_t)((ks * 4 + rt) * 64 + lane) * 8);
#pragma unroll
    for (int ct = 0; ct < 4; ct++) {
      if (ks < 2)
        bf[ct] = uf[ct][ks];
      else
        bf[ct] = *(const f16x8*)&Sl[w][ct][cl][(ks - 2) * 32 + k8 * 8];
    }
#pragma unroll
    for (int rt = 0; rt < 4; rt++)
#pragma unroll
      for (int ct = 0; ct < 4; ct++)
        accD[rt][ct] =
            __builtin_amdgcn_mfma_f32_16x16x32_f16(af[rt], bf[ct], accD[rt][ct], 0, 0, 0);
  }

  // ---- epilogue: GELU + coalesced store (B,H,L)
#pragma unroll
  for (int ct = 0; ct < 4; ct++) {
    int col = col0 + ct * 16 + cl;
    int b = col >> 4, c = col & 15;
    f16* yp = yout + (size_t)(b * kH + h) * kL + c * 64;
#pragma unroll
    for (int rt = 0; rt < 4; rt++) {
      f16x4 v;
#pragma unroll
      for (int reg = 0; reg < 4; reg++) v[reg] = (f16)gelu_tanh(accD[rt][ct][reg]);
      *(f16x4*)(yp + rt * 16 + k8 * 4) = v;
    }
  }
}

// ---------------------------------------------------------------------------
// K4: GLU GEMM v3. A-fragments direct from fragment-ordered woF (L2-resident,
// no LDS, no barrier dependency). B double-buffered in LDS (2x16KB): per
// K-step, prefetch B_{k+1} right AFTER the barrier so its latency overlaps
// compute_k; the next barrier is the drain point.
// Block: 128 A-rows (64 h x both GLU halves) x 128 l, K=512, 8 K-steps.
// ---------------------------------------------------------------------------
__global__ __launch_bounds__(256) void glu_mfma_kernel(
    const f16* __restrict__ yt,   // (B, L, H)
    const f16* __restrict__ woF,  // fragment-ordered Wo, this layer
    const float* __restrict__ bo, // (2H,)
    f16* __restrict__ uout) {     // (B, H, L)
  __shared__ __align__(16) f16 Bt[2][16][64][8];
  int tid = threadIdx.x;
  int lane = tid & 63, w = tid >> 6;
  int wm = w >> 1, wn = w & 1;
  int lr = lane & 15, lc = lane >> 4;
  int b = blockIdx.z, h0 = blockIdx.y * 64, l0 = blockIdx.x * 128;
  // B staging source for this wave's 4 subtiles (st = w*4+i; nt=st>>1, ks2=st&1)
  const f16* gB[4];
#pragma unroll
  for (int i = 0; i < 4; ++i) {
    int st = w * 4 + i, nt = st >> 1, ks2 = st & 1;
    gB[i] = yt + ((size_t)b * kL + l0 + nt * 16 + lr) * kH + ks2 * 32 + lc * 8;
  }
  // A fragment pointers: 4 m-subtiles for this wave (2 per GLU half)
  const f16* gA[4];
#pragma unroll
  for (int i = 0; i < 4; ++i) {
    int mt = (i < 2) ? ((h0 >> 4) + wm * 2 + i) : (32 + (h0 >> 4) + wm * 2 + (i - 2));
    gA[i] = woF + ((size_t)mt * 16 * 64 + lane) * 8;
  }

  f32x4 acc[4][4] = {};

  // prologue: stage B tile 0
#pragma unroll
  for (int i = 0; i < 4; ++i) llds16(gB[i], &Bt[0][w * 4 + i][0][0]);

  for (int kk = 0; kk < 8; ++kk) {
    __syncthreads();  // drains B_kk
    if (kk < 7) {
#pragma unroll
      for (int i = 0; i < 4; ++i)
        llds16(gB[i] + (kk + 1) * 64, &Bt[(kk + 1) & 1][w * 4 + i][0][0]);
    }
    int buf = kk & 1;
#pragma unroll
    for (int ks = 0; ks < 2; ++ks) {
      int ksg = kk * 2 + ks;
      f16x8 av[4], bv[4];
#pragma unroll
      for (int i = 0; i < 4; ++i)
        av[i] = *(const f16x8*)(gA[i] + (size_t)ksg * 64 * 8);
#pragma unroll
      for (int nt = 0; nt < 4; ++nt)
        bv[nt] = *(const f16x8*)Bt[buf][(wn * 4 + nt) * 2 + ks][lane];
#pragma unroll
      for (int i = 0; i < 4; ++i)
#pragma unroll
        for (int nt = 0; nt < 4; ++nt)
          acc[i][nt] =
              __builtin_amdgcn_mfma_f32_16x16x32_f16(av[i], bv[nt], acc[i][nt], 0, 0, 0);
    }
  }

  int col = lane & 15, q = lane >> 4;
  f16* ub = uout + (size_t)b * kH * kL;
#pragma unroll
  for (int i = 0; i < 2; ++i) {
#pragma unroll
    for (int reg = 0; reg < 4; ++reg) {
      int h = h0 + wm * 32 + i * 16 + q * 4 + reg;
      float b1 = bo[h], b2 = bo[h + kH];
#pragma unroll
      for (int nt = 0; nt < 4; ++nt) {
        float z1 = acc[i][nt][reg] + b1;
        float z2 = acc[i + 2][nt][reg] + b2;
        float sg = 1.f / (1.f + __expf(-z2));
        ub[(size_t)h * kL + l0 + wn * 64 + nt * 16 + col] = (f16)(z1 * sg);
      }
    }
  }
}

// ---------------------------------------------------------------------------
// K5: final projection via MFMA f16 (unchanged).
// ---------------------------------------------------------------------------
__global__ __launch_bounds__(256) void final_mfma_kernel(
    const f16* __restrict__ x, const f16* __restrict__ wout,
    const float* __restrict__ bout, float* __restrict__ outp) {
  __shared__ __align__(16) f16 At[16][64][8];
  __shared__ __align__(16) f16 Bt[16][64][8];
  int tid = threadIdx.x;
  int lane = tid & 63, w = tid >> 6;
  int wm = w >> 1, wn = w & 1;
  int lr = lane & 15, lc = lane >> 4;
  int b = blockIdx.z, p0 = blockIdx.y * 128, h0 = blockIdx.x * 128;
  const f16* xb = x + (size_t)b * kH * kL;

  f32x4 acc[4][4] = {};

  const f16* gA[4];
  const f16* gB[4];
#pragma unroll
  for (int i = 0; i < 4; ++i) {
    int st = w * 4 + i, mt = st >> 1, ks = st & 1;
    int prow = p0 + mt * 16 + lr;
    if (prow > kP - 1) prow = kP - 1;
    gA[i] = wout + (size_t)prow * kL + ks * 32 + lc * 8;
    int hrow = h0 + mt * 16 + lr;
    gB[i] = xb + (size_t)hrow * kL + ks * 32 + lc * 8;
  }

  for (int k0 = 0; k0 < kL; k0 += 64) {
#pragma unroll
    for (int i = 0; i < 4; ++i) {
      int st = w * 4 + i;
      llds16(gA[i] + k0, &At[st][0][0]);
      llds16(gB[i] + k0, &Bt[st][0][0]);
    }
    __syncthreads();
#pragma unroll
    for (int ks = 0; ks < 2; ++ks) {
      f16x8 av[4], bv[4];
#pragma unroll
      for (int i = 0; i < 4; ++i)
        av[i] = *(const f16x8*)At[(wm * 4 + i) * 2 + ks][lane];
#pragma unroll
      for (int nt = 0; nt < 4; ++nt)
        bv[nt] = *(const f16x8*)Bt[(wn * 4 + nt) * 2 + ks][lane];
#pragma unroll
      for (int i = 0; i < 4; ++i)
#pragma unroll
        for (int nt = 0; nt < 4; ++nt)
          acc[i][nt] =
              __builtin_amdgcn_mfma_f32_16x16x32_f16(av[i], bv[nt], acc[i][nt], 0, 0, 0);
    }
    __syncthreads();
  }

  int col = lane & 15, q = lane >> 4;
  float* ob = outp + (size_t)b * kP * kH;
#pragma unroll
  for (int i = 0; i < 4; ++i) {
#pragma unroll
    for (int reg = 0; reg < 4; ++reg) {
      int p = p0 + wm * 64 + i * 16 + q * 4 + reg;
      if (p < kP) {
        float bv2 = bout[p];
#pragma unroll
        for (int nt = 0; nt < 4; ++nt)
          ob[(size_t)p * kH + h0 + wn * 64 + nt * 16 + col] = acc[i][nt][reg] + bv2;
      }
    }
  }
}

}  // namespace

extern "C" void kernel_launch(void* const* d_in, const int* in_sizes, int n_in,
                              void* d_out, int out_size, void* d_ws, size_t ws_size,
                              hipStream_t stream) {
  const float* x_enc  = (const float*)d_in[0];
  const float* log_dt = (const float*)d_in[4];
  const float* A_re   = (const float*)d_in[5];
  const float* A_im   = (const float*)d_in[6];
  const float* C_re   = (const float*)d_in[7];
  const float* C_im   = (const float*)d_in[8];
  const float* Dskip  = (const float*)d_in[9];
  const float* Wo     = (const float*)d_in[10];
  const float* bo     = (const float*)d_in[11];
  const float* W_out  = (const float*)d_in[12];
  const float* b_out  = (const float*)d_in[13];
  float* out = (float*)d_out;

  char* wsb = (char*)d_ws;
  f16* u16    = (f16*)(wsb);                   // 32 MB: u (B,H,L)
  f16* ybuf   = (f16*)(wsb + 33554432);        // 32 MB: y (B,H,L)
  f16* S16    = (f16*)(wsb + 67108864);        // 32 MB: yt (B,L,H)
  f16* woF    = (f16*)(wsb + 100663296);       // 3 MB fragment-ordered Wo
  f16* wout16 = (f16*)(wsb + 103809024);       // 672 KB
  f16* afc    = (f16*)(wsb + 104497152);       // 24 MB  [lh][16][64][8]
  f16* afa    = (f16*)(wsb + 129662976);       // 12 MB  [lh][8][64][8]
  float* rT   = (float*)(wsb + 142245888);     // 384 KB [lh][32][2]

  const int nwp = kP * kL;
  f32_to_f16_kernel<<<(nwp + 255) / 256, 256, 0, stream>>>(W_out, wout16, nwp);
  wo_frag_kernel<<<dim3(64, kNL), 256, 0, stream>>>(Wo, woF);

  prep_kernel<<<kNL * kH, 64, 0, stream>>>(log_dt, A_re, A_im, C_re, C_im, Dskip,
                                           afc, afa, rT);

  transpose_kernel<<<dim3(kL / 32, kH / 32, kB), dim3(32, 8), 0, stream>>>(x_enc, u16);

  for (int layer = 0; layer < kNL; layer++) {
    chunk_wy_kernel<<<dim3(2, kH), 256, 0, stream>>>(u16, afa, afc, rT, ybuf, layer);
    t16_kernel<<<dim3(kL / 64, kH / 64, kB), 256, 0, stream>>>(ybuf, S16);
    glu_mfma_kernel<<<dim3(kL / 128, kH / 64, kB), 256, 0, stream>>>(
        S16, woF + (size_t)layer * 64 * 8192, bo + (size_t)layer * 2 * kH, u16);
  }

  final_mfma_kernel<<<dim3(kH / 128, 3, kB), 256, 0, stream>>>(u16, wout16, b_out, out);
}